// Round 6
// baseline (493.177 us; speedup 1.0000x reference)
//
#include <hip/hip_runtime.h>

typedef unsigned short ushort_t;
typedef unsigned int uint32;
typedef __bf16 bf16x8 __attribute__((ext_vector_type(8)));
typedef float f32x4 __attribute__((ext_vector_type(4)));
typedef uint32 u32x4 __attribute__((ext_vector_type(4)));
typedef uint32 u32x2 __attribute__((ext_vector_type(2)));

__device__ __forceinline__ float bf2f(ushort_t u) {
    uint32 x = ((uint32)u) << 16;
    return __builtin_bit_cast(float, x);
}
__device__ __forceinline__ ushort_t f2bf(float f) {
    uint32 x = __builtin_bit_cast(uint32, f);
    x += 0x7fffu + ((x >> 16) & 1u);   // RNE
    return (ushort_t)(x >> 16);
}

// dtype sniffer (validated r3/r4): 1 = f32 inputs, 0 = bf16 inputs
__global__ void sniff_kernel(const uint32* __restrict__ src, int* __restrict__ flag) {
    __shared__ int cnt;
    if (threadIdx.x == 0) cnt = 0;
    __syncthreads();
    int weird = 0;
    for (int c = 0; c < 4; c++) {
        uint32 w = src[threadIdx.x * 4 + c];
        uint32 e = (w >> 7) & 0xFFu;
        weird += (e < 64u) || (e >= 192u);
    }
    atomicAdd(&cnt, weird);
    __syncthreads();
    if (threadIdx.x == 0) *flag = (cnt > 32) ? 1 : 0;
}

// fused small-vector canon: 13 arrays in one launch
struct VecArgs { const void* s[13]; ushort_t* d[13]; int n[13]; };
__global__ void vec_canon_kernel(VecArgs a, const int* __restrict__ flag) {
    const bool isf32 = (*flag != 0);
    const int t = threadIdx.x;
    for (int seg = 0; seg < 13; seg++) {
        const int n = a.n[seg];
        if (isf32) {
            const float* s = (const float*)a.s[seg];
            for (int i = t; i < n; i += 256) a.d[seg][i] = f2bf(s[i]);
        } else {
            const ushort_t* s = (const ushort_t*)a.s[seg];
            for (int i = t; i < n; i += 256) a.d[seg][i] = s[i];
        }
    }
}

// fused weight transpose-canon: 5 weights, one launch (z = segment).
// dst[C][R] = src[R][C], bf16 out. 128 32x32 tiles per segment.
struct WtArgs { const void* s[5]; ushort_t* d[5]; int R[5]; int C[5]; };
__global__ void wt_canon_kernel(WtArgs a, const int* __restrict__ flag) {
    __shared__ float s[32][33];
    const bool isf32 = (*flag != 0);
    const int seg = blockIdx.z;
    const int R = a.R[seg], C = a.C[seg];
    const int nR = R >> 5;
    const int t = blockIdx.x;
    const int tr = t % nR, tc = t / nR;
    const int tt = threadIdx.x;
    const int r = tt >> 3, c4 = (tt & 7) * 4;
    const long sbase = (long)(tr * 32 + r) * C + tc * 32 + c4;
    if (isf32) {
        const float* S = (const float*)a.s[seg];
        const f32x4 v = *(const f32x4*)(S + sbase);
        for (int u = 0; u < 4; u++) s[r][c4 + u] = v[u];
    } else {
        const ushort_t* S = (const ushort_t*)a.s[seg];
        for (int u = 0; u < 4; u++) s[r][c4 + u] = bf2f(S[sbase + u]);
    }
    __syncthreads();
    ushort_t tmp[4];
    for (int u = 0; u < 4; u++) tmp[u] = f2bf(s[c4 + u][r]);
    u32x2 pk;
    pk[0] = (uint32)tmp[0] | ((uint32)tmp[1] << 16);
    pk[1] = (uint32)tmp[2] | ((uint32)tmp[3] << 16);
    *(u32x2*)(a.d[seg] + (long)(tc * 32 + r) * R + tr * 32 + c4) = pk;
}

// reduce all 64 fp32 split-K partials: out[g*65536+i] = bf16(sum_{kc<4} P[(g*4+kc)*65536+i])
__global__ void reduce_all_kernel(const float* __restrict__ P, ushort_t* __restrict__ out) {
    const long nq = 16L * 65536 / 4;
    long i = (long)blockIdx.x * blockDim.x + threadIdx.x;
    const long stride = (long)gridDim.x * blockDim.x;
    for (; i < nq; i += stride) {
        const long g = i / 16384, e = (i % 16384) * 4;
        const float* base = P + g * 4 * 65536 + e;
        f32x4 acc = {0.f, 0.f, 0.f, 0.f};
        for (int kc = 0; kc < 4; kc++) acc += *(const f32x4*)(base + (long)kc * 65536);
        u32x2 pk;
        pk[0] = (uint32)f2bf(acc[0]) | ((uint32)f2bf(acc[1]) << 16);
        pk[1] = (uint32)f2bf(acc[2]) | ((uint32)f2bf(acc[3]) << 16);
        *(u32x2*)(out + g * 65536 + e) = pk;
    }
}

#define BM 128
#define BN 128
#define BK 32
#define LDSS 40

enum { EPI_BIAS = 0, EPI_SCALE = 1, EPI_BN = 2, EPI_PART = 3 };
// TMODE: 0 = normal store, 1 = normal + transposed, 2 = transposed only

// NT GEMM: C[m][n] = sum_k A[m][k]*B[n][k]. B always bf16, k-contiguous.
// DYNA: A dtype per *flag (converted during LDS staging).
// DYNOUT: output + res dtype per *flag. EPI_PART: fp32 partial store.
// res is indexed with (off - coff): same batch stride sC, but without the
// d_out-internal offset (r5 crash root cause).
template <int EPI, int TMODE, bool DYNA, bool DYNOUT>
__global__ __launch_bounds__(256) void gemm_nt(
    const void* __restrict__ Av, const ushort_t* __restrict__ B,
    void* __restrict__ Cv, long coff,
    int K, int lda, int ldb, int ldc,
    long sA, long sB, long sC,
    ushort_t* __restrict__ CT, int ldT,
    const ushort_t* __restrict__ bias,
    const ushort_t* __restrict__ gamma, const ushort_t* __restrict__ beta,
    const ushort_t* __restrict__ mean, const ushort_t* __restrict__ var,
    const void* __restrict__ res,
    float alpha, const int* __restrict__ flag)
{
    __shared__ __align__(16) ushort_t As[BM * LDSS];
    __shared__ __align__(16) ushort_t Bs[BN * LDSS];

    const bool isf32 = (DYNA || DYNOUT) ? (*flag != 0) : false;

    const int z = blockIdx.z;
    const long abase = (long)z * sA;
    B += (long)z * sB;
    const long cbase = coff + (long)z * sC;

    const int tid  = threadIdx.x;
    const int lane = tid & 63;
    const int w    = tid >> 6;
    const int wr   = w >> 1, wc = w & 1;
    const int lr   = lane & 15, q = lane >> 4;

    const int m0 = blockIdx.y * BM;
    const int n0 = blockIdx.x * BN;

    f32x4 acc[4][4];
#pragma unroll
    for (int i = 0; i < 4; i++)
#pragma unroll
        for (int j = 0; j < 4; j++) acc[i][j] = (f32x4){0.f, 0.f, 0.f, 0.f};

    for (int k0 = 0; k0 < K; k0 += BK) {
        // ---- stage A ----
        if (DYNA && isf32) {
            const float* Af = (const float*)Av + abase;
#pragma unroll
            for (int c = 0; c < 2; c++) {
                const int ch = tid + c * 256;
                const int r = ch >> 2, qq = ch & 3;
                const float* p = Af + (long)(m0 + r) * lda + k0 + qq * 8;
                const f32x4 v0 = *(const f32x4*)(p);
                const f32x4 v1 = *(const f32x4*)(p + 4);
                u32x4 pk;
                pk[0] = (uint32)f2bf(v0[0]) | ((uint32)f2bf(v0[1]) << 16);
                pk[1] = (uint32)f2bf(v0[2]) | ((uint32)f2bf(v0[3]) << 16);
                pk[2] = (uint32)f2bf(v1[0]) | ((uint32)f2bf(v1[1]) << 16);
                pk[3] = (uint32)f2bf(v1[2]) | ((uint32)f2bf(v1[3]) << 16);
                *(u32x4*)(&As[r * LDSS + qq * 8]) = pk;
            }
        } else {
            const ushort_t* Ab = (const ushort_t*)Av + abase;
#pragma unroll
            for (int c = 0; c < 2; c++) {
                const int ch = tid + c * 256;
                const int r = ch >> 2, qq = ch & 3;
                *(u32x4*)(&As[r * LDSS + qq * 8]) =
                    *(const u32x4*)(Ab + (long)(m0 + r) * lda + k0 + qq * 8);
            }
        }
        // ---- stage B ----
#pragma unroll
        for (int c = 0; c < 2; c++) {
            const int ch = tid + c * 256;
            const int r = ch >> 2, qq = ch & 3;
            *(u32x4*)(&Bs[r * LDSS + qq * 8]) =
                *(const u32x4*)(B + (long)(n0 + r) * ldb + k0 + qq * 8);
        }
        __syncthreads();

        bf16x8 af[4], bfr[4];
#pragma unroll
        for (int i = 0; i < 4; i++)
            af[i] = __builtin_bit_cast(bf16x8,
                *(const u32x4*)(&As[(wr * 64 + i * 16 + lr) * LDSS + q * 8]));
#pragma unroll
        for (int j = 0; j < 4; j++)
            bfr[j] = __builtin_bit_cast(bf16x8,
                *(const u32x4*)(&Bs[(wc * 64 + j * 16 + lr) * LDSS + q * 8]));
#pragma unroll
        for (int i = 0; i < 4; i++)
#pragma unroll
            for (int j = 0; j < 4; j++)
                acc[i][j] = __builtin_amdgcn_mfma_f32_16x16x32_bf16(af[i], bfr[j], acc[i][j], 0, 0, 0);
        __syncthreads();
    }

    // D layout: col=lane&15, row=(lane>>4)*4+reg  [verified]
#pragma unroll
    for (int j = 0; j < 4; j++) {
        const int col = n0 + wc * 64 + j * 16 + lr;
        float bs = 0.f, sc = 1.f, sh = 0.f;
        if constexpr (EPI == EPI_BIAS || EPI == EPI_BN) bs = bf2f(bias[col]);
        if constexpr (EPI == EPI_BN) {
            const float g  = bf2f(gamma[col]);
            const float bt = bf2f(beta[col]);
            const float mn = bf2f(mean[col]);
            const float vr = bf2f(var[col]);
            sc = g * rsqrtf(vr + 1e-3f);
            sh = bt - sc * mn;
        }
#pragma unroll
        for (int i = 0; i < 4; i++) {
            const int rowbase = m0 + wr * 64 + i * 16 + q * 4;
            ushort_t tmp[4];
#pragma unroll
            for (int r = 0; r < 4; r++) {
                float v = acc[i][j][r];
                const long off = cbase + (long)(rowbase + r) * ldc + col;
                if constexpr (EPI == EPI_BIAS) v += bs;
                else if constexpr (EPI == EPI_SCALE) v *= alpha;
                else if constexpr (EPI == EPI_BN) {
                    const long roff = off - coff;   // residual lives outside d_out
                    const float rv = isf32 ? ((const float*)res)[roff]
                                           : bf2f(((const ushort_t*)res)[roff]);
                    v = sc * (v + bs) + sh + rv;
                }
                if constexpr (EPI == EPI_PART) {
                    ((float*)Cv)[off] = v;
                } else if constexpr (DYNOUT) {
                    if (isf32) ((float*)Cv)[off] = v;
                    else       ((ushort_t*)Cv)[off] = f2bf(v);
                } else {
                    const ushort_t us = f2bf(v);
                    if constexpr (TMODE != 2) ((ushort_t*)Cv)[off] = us;
                    if constexpr (TMODE >= 1) tmp[r] = us;
                }
            }
            if constexpr (TMODE >= 1) {
                u32x2 pk;
                pk[0] = (uint32)tmp[0] | ((uint32)tmp[1] << 16);
                pk[1] = (uint32)tmp[2] | ((uint32)tmp[3] << 16);
                *(u32x2*)(CT + (long)col * ldT + rowbase) = pk;
            }
        }
    }
}

extern "C" void kernel_launch(void* const* d_in, const int* in_sizes, int n_in,
                              void* d_out, int out_size, void* d_ws, size_t ws_size,
                              hipStream_t stream)
{
    int* flag = (int*)d_ws;
    ushort_t* base = (ushort_t*)((char*)d_ws + 16);
    long o = 0;
    ushort_t* WgT  = base + o; o += 131072;   // [256][512]
    ushort_t* WtT  = base + o; o += 131072;   // [256][512]
    ushort_t* WpT  = base + o; o += 131072;   // [256][512]
    ushort_t* WwT  = base + o; o += 131072;   // [512][256]
    ushort_t* WqT  = base + o; o += 131072;   // [512][256]
    ushort_t* bg_c   = base + o; o += 256;
    ushort_t* bt_c   = base + o; o += 256;
    ushort_t* bp_c   = base + o; o += 256;
    ushort_t* bw_c   = base + o; o += 512;
    ushort_t* gw_c   = base + o; o += 512;
    ushort_t* betw_c = base + o; o += 512;
    ushort_t* mw_c   = base + o; o += 512;
    ushort_t* vw_c   = base + o; o += 512;
    ushort_t* bq_c   = base + o; o += 512;
    ushort_t* gq_c   = base + o; o += 512;
    ushort_t* betq_c = base + o; o += 512;
    ushort_t* mq_c   = base + o; o += 512;
    ushort_t* vq_c   = base + o; o += 512;
    ushort_t* phi    = base + o; o += 8388608;   // [32768][256]
    ushort_t* phiT   = base + o; o += 8388608;   // [256][32768]
    ushort_t* d_xT   = base + o; o += 8388608;   // [256][32768]
    ushort_t* theta  = base + o; o += 2097152;   // [8192][256]
    ushort_t* thetaT = base + o; o += 2097152;   // [256][8192]
    ushort_t* a_xT   = base + o; o += 2097152;   // [256][8192]
    ushort_t* Pr     = base + o; o += 8388608;   // P1,P2: 64 x 65536 fp32
    float* P1 = (float*)Pr;
    float* P2 = P1 + 32L * 65536;
    ushort_t* G1  = base + o; o += 524288;       // [8][256][256]  (G2 follows)
    ushort_t* G2  = base + o; o += 524288;
    ushort_t* H1T = base + o; o += 1048576;      // [8][512][256]
    ushort_t* H2T = base + o; o += 1048576;      // total ~84 MB

    sniff_kernel<<<1, 64, 0, stream>>>((const uint32*)d_in[0], flag);

    VecArgs va;
    const int vidx[13] = {3, 5, 7, 9, 10, 11, 12, 13, 15, 16, 17, 18, 19};
    ushort_t* vdst[13] = {bg_c, bt_c, bp_c, bw_c, gw_c, betw_c, mw_c, vw_c,
                          bq_c, gq_c, betq_c, mq_c, vq_c};
    const int vn[13] = {256, 256, 256, 512, 512, 512, 512, 512, 512, 512, 512, 512, 512};
    for (int i = 0; i < 13; i++) { va.s[i] = d_in[vidx[i]]; va.d[i] = vdst[i]; va.n[i] = vn[i]; }
    vec_canon_kernel<<<1, 256, 0, stream>>>(va, flag);

    WtArgs wa;
    wa.s[0] = d_in[2];  wa.d[0] = WgT; wa.R[0] = 512; wa.C[0] = 256;
    wa.s[1] = d_in[4];  wa.d[1] = WtT; wa.R[1] = 512; wa.C[1] = 256;
    wa.s[2] = d_in[6];  wa.d[2] = WpT; wa.R[2] = 512; wa.C[2] = 256;
    wa.s[3] = d_in[8];  wa.d[3] = WwT; wa.R[3] = 256; wa.C[3] = 512;
    wa.s[4] = d_in[14]; wa.d[4] = WqT; wa.R[4] = 256; wa.C[4] = 512;
    wt_canon_kernel<<<dim3(128, 1, 5), 256, 0, stream>>>(wa, flag);

    const dim3 blk(256);
    const ushort_t* np = nullptr;
    ushort_t* npm = nullptr;

    // conv phi = detect @ Wp + bp : normal [32768][256] + T [256][32768]
    gemm_nt<EPI_BIAS, 1, true, false><<<dim3(2, 256, 1), blk, 0, stream>>>(
        d_in[0], WpT, phi, 0, 512, 512, 512, 256, 0, 0, 0,
        phiT, 32768, bp_c, np, np, np, np, nullptr, 1.f, flag);
    // conv theta = aim @ Wt + bt : normal + T
    gemm_nt<EPI_BIAS, 1, true, false><<<dim3(2, 64, 1), blk, 0, stream>>>(
        d_in[1], WtT, theta, 0, 512, 512, 512, 256, 0, 0, 0,
        thetaT, 8192, bt_c, np, np, np, np, nullptr, 1.f, flag);
    // conv d_x = detect @ Wg + bg : T only
    gemm_nt<EPI_BIAS, 2, true, false><<<dim3(2, 256, 1), blk, 0, stream>>>(
        d_in[0], WgT, npm, 0, 512, 512, 512, 256, 0, 0, 0,
        d_xT, 32768, bg_c, np, np, np, np, nullptr, 1.f, flag);
    // conv a_x = aim @ Wg + bg : T only
    gemm_nt<EPI_BIAS, 2, true, false><<<dim3(2, 64, 1), blk, 0, stream>>>(
        d_in[1], WgT, npm, 0, 512, 512, 512, 256, 0, 0, 0,
        a_xT, 8192, bg_c, np, np, np, np, nullptr, 1.f, flag);

    // G1 partials: z=b*4+kc, K-chunk 1024 (batch stride 4096 = 4*1024)
    gemm_nt<EPI_PART, 0, false, false><<<dim3(2, 2, 32), blk, 0, stream>>>(
        phiT, d_xT, P1, 0, 1024, 32768, 32768, 256, 1024, 1024, 65536,
        npm, 0, np, np, np, np, np, nullptr, 1.f, flag);
    // G2 partials: K-chunk 256 (batch stride 1024 = 4*256)
    gemm_nt<EPI_PART, 0, false, false><<<dim3(2, 2, 32), blk, 0, stream>>>(
        thetaT, a_xT, P2, 0, 256, 8192, 8192, 256, 256, 256, 65536,
        npm, 0, np, np, np, np, np, nullptr, 1.f, flag);

    // reduce both partial sets -> G1,G2 (contiguous)
    reduce_all_kernel<<<512, 256, 0, stream>>>(P1, G1);

    // H1T[b] = WwT @ G1[b] / 4096  (M=512,N=256,K=256)
    gemm_nt<EPI_SCALE, 0, false, false><<<dim3(2, 4, 8), blk, 0, stream>>>(
        WwT, G1, H1T, 0, 256, 256, 256, 256, 0, 65536, 131072,
        npm, 0, np, np, np, np, np, nullptr, 1.f / 4096.f, flag);
    // H2T[b] = WqT @ G2[b] / 1024
    gemm_nt<EPI_SCALE, 0, false, false><<<dim3(2, 4, 8), blk, 0, stream>>>(
        WqT, G2, H2T, 0, 256, 256, 256, 256, 0, 65536, 131072,
        npm, 0, np, np, np, np, np, nullptr, 1.f / 1024.f, flag);

    // out0 = BN(theta @ H1T + bw) + aim   (z=batch, M=1024/z)
    gemm_nt<EPI_BN, 0, false, true><<<dim3(4, 8, 8), blk, 0, stream>>>(
        theta, H1T, d_out, 0, 256, 256, 256, 512,
        1024L * 256, 131072, 1024L * 512,
        npm, 0, bw_c, gw_c, betw_c, mw_c, vw_c, d_in[1], 1.f, flag);
    // out1 = BN(phi @ H2T + bq) + detect  (z=batch, M=4096/z)
    gemm_nt<EPI_BN, 0, false, true><<<dim3(4, 32, 8), blk, 0, stream>>>(
        phi, H2T, d_out, 8192L * 512, 256, 256, 256, 512,
        4096L * 256, 131072, 4096L * 512,
        npm, 0, bq_c, gq_c, betq_c, mq_c, vq_c, d_in[0], 1.f, flag);
}